// Round 2
// baseline (877.579 us; speedup 1.0000x reference)
//
#include <hip/hip_runtime.h>

#define RR 32
#define R3 32768
#define BATCH 8
#define CH 64
#define NPTS 100000
#define NPOINTS (BATCH * NPTS)   // 800000
#define NVOX (BATCH * R3)        // 262144
#define NTILE 1563               // ceil(100000 / 64) point tiles per batch
#define CHUNK 512                // voxels per reduce block
#define NCHUNK (R3 / CHUNK)      // 64 chunks per batch

typedef unsigned int uint32;
typedef unsigned short uint16;

__device__ __forceinline__ uint32 f2bf(float f) {
    uint32 u = __float_as_uint(f);
    return (u + 0x7fffu + ((u >> 16) & 1u)) >> 16;   // RNE to bf16
}
__device__ __forceinline__ float bf2f(uint32 h) {
    return __uint_as_float(h << 16);
}

// ---------------------------------------------------------------------------
// K1: voxelize — NO atomics, pure streaming. vox ids + coord output.
// ---------------------------------------------------------------------------
__global__ __launch_bounds__(256) void voxelize(
    const float* __restrict__ coords,  // [B, 3, N]
    uint16* __restrict__ vox,          // [NPOINTS] local voxel id (0..32767)
    float* __restrict__ out2)          // [B, 3, N] voxel coords as float
{
    int gid = blockIdx.x * blockDim.x + threadIdx.x;
    if (gid >= NPOINTS) return;
    int b = gid / NPTS;
    int n = gid - b * NPTS;

    const float* cb = coords + (size_t)b * 3 * NPTS + n;
    float fx = fminf(fmaxf(cb[0]        * 32.0f, 0.0f), 31.0f);
    float fy = fminf(fmaxf(cb[NPTS]     * 32.0f, 0.0f), 31.0f);
    float fz = fminf(fmaxf(cb[2 * NPTS] * 32.0f, 0.0f), 31.0f);
    int x = (int)rintf(fx);   // round-half-even matches jnp.round
    int y = (int)rintf(fy);
    int z = (int)rintf(fz);
    int v = x * (RR * RR) + y * RR + z;

    float* o2 = out2 + (size_t)b * 3 * NPTS + n;
    o2[0]        = (float)x;
    o2[NPTS]     = (float)y;
    o2[2 * NPTS] = (float)z;

    vox[gid] = (uint16)v;
}

// ---------------------------------------------------------------------------
// K2: transpose feat [B,C,N] f32 -> featT [B,N,C] bf16 (coalesced both sides).
// Tile = 64 channels x 64 points, LDS fp32 [64][65].
// ---------------------------------------------------------------------------
__global__ __launch_bounds__(256) void transpose_bf16(
    const float* __restrict__ feat,    // [B, C, N]
    uint16* __restrict__ featT)        // [B, N, C] bf16
{
    __shared__ float tile[64][65];

    int b    = blockIdx.x / NTILE;
    int t    = blockIdx.x - b * NTILE;
    int n0   = t * 64;
    int tid  = threadIdx.x;

    // read: wave cq covers channels cq*16..cq*16+15, lane i = point
    int i  = tid & 63;
    int cq = tid >> 6;          // 0..3
    const float* fb = feat + (size_t)b * CH * NPTS;
    int n = n0 + i;
    bool ok = (n < NPTS);
#pragma unroll
    for (int k = 0; k < 16; ++k) {
        int c = cq * 16 + k;
        float v = ok ? fb[(size_t)c * NPTS + n] : 0.0f;
        tile[c][i] = v;
    }
    __syncthreads();

    // write: 8 lanes per row (q = uint4 slot), 8 rows per wave -> coalesced 1 KB
    int q = tid & 7;
#pragma unroll
    for (int h = 0; h < 2; ++h) {
        int r = (tid >> 3) + 32 * h;        // 0..63
        int nr = n0 + r;
        if (nr < NPTS) {
            uint4 wv;
            wv.x = f2bf(tile[8*q+0][r]) | (f2bf(tile[8*q+1][r]) << 16);
            wv.y = f2bf(tile[8*q+2][r]) | (f2bf(tile[8*q+3][r]) << 16);
            wv.z = f2bf(tile[8*q+4][r]) | (f2bf(tile[8*q+5][r]) << 16);
            wv.w = f2bf(tile[8*q+6][r]) | (f2bf(tile[8*q+7][r]) << 16);
            ((uint4*)featT)[((size_t)b * NPTS + nr) * 8 + q] = wv;
        }
    }
}

// ---------------------------------------------------------------------------
// K3: chunk-reduce. One block per (batch, 512-voxel chunk); 8 waves, each
// wave OWNS 64 voxels (64 rows of acc) -> plain LDS read-add-write, no
// atomics, no races. Each wave re-scans the batch's voxel-id stream (200 KB,
// L1/L2-resident); hits are rare (~195/wave). Hit: coalesced 128 B featT row
// (lane = channel) accumulated into conflict-free acc[row][lane].
// ---------------------------------------------------------------------------
__global__ __launch_bounds__(512) void chunk_reduce(
    const uint16* __restrict__ vox,    // [B*N]
    const uint16* __restrict__ featT,  // [B, N, C] bf16
    float* __restrict__ out1)          // [B, C, R3]
{
    extern __shared__ float acc[];     // [CHUNK][65] = 133120 B
    __shared__ uint32 counts[CHUNK];

    int b        = blockIdx.x >> 6;
    int chunk    = blockIdx.x & 63;
    int chunk_lo = chunk * CHUNK;
    int tid      = threadIdx.x;
    int w        = tid >> 6;           // wave 0..7
    int lane     = tid & 63;
    uint32 lo    = (uint32)(chunk_lo + w * 64);   // this wave's voxel range

    // zero acc (512 threads x 65) and counts
#pragma unroll
    for (int k = 0; k < 65; ++k) acc[k * CHUNK + tid] = 0.0f;
    counts[tid & (CHUNK - 1)] = 0u;    // tid 0..511 covers all
    __syncthreads();

    const uint2*  voxb2  = (const uint2*)(vox + (size_t)b * NPTS);   // 4 ids/uint2
    const uint16* featTb = featT + (size_t)b * NPTS * CH;

    const int NU2 = NPTS / 4;          // 25000
    for (int j = 0; j < (NU2 + 63) / 64; ++j) {
        int qi = j * 64 + lane;
        uint2 d = (qi < NU2) ? voxb2[qi] : make_uint2(0xffffffffu, 0xffffffffu);
        uint32 v0 = d.x & 0xffffu, v1 = d.x >> 16;
        uint32 v2 = d.y & 0xffffu, v3 = d.y >> 16;
        bool hit = ((v0 - lo) < 64u) | ((v1 - lo) < 64u) |
                   ((v2 - lo) < 64u) | ((v3 - lo) < 64u);
        unsigned long long m = __ballot(hit);
        while (m) {
            int l = __ffsll(m) - 1;
            m &= m - 1;
            uint32 ax = __shfl(d.x, l);
            uint32 ay = __shfl(d.y, l);
            int nb = (j * 64 + l) * 4;
            uint32 vv0 = ax & 0xffffu, vv1 = ax >> 16;
            uint32 vv2 = ay & 0xffffu, vv3 = ay >> 16;
#pragma unroll
            for (int e = 0; e < 4; ++e) {
                uint32 ve = (e == 0) ? vv0 : (e == 1) ? vv1 : (e == 2) ? vv2 : vv3;
                uint32 dv = ve - lo;                  // wave-uniform
                if (dv < 64u) {
                    int n = nb + e;
                    float val = bf2f(featTb[(size_t)n * CH + lane]); // 128 B coalesced
                    int row = w * 64 + (int)dv;       // wave-private rows
                    acc[row * 65 + lane] += val;      // bank (row+lane)%32: free
                    if (lane == 0) counts[row]++;
                }
            }
        }
    }
    __syncthreads();

    // finalize: divide by count, coalesced write out1[b][c][chunk_lo + vv]
    int vv = tid;                                     // 0..511
    uint32 cc = counts[vv];
    float rcp = 1.0f / (float)(cc > 1u ? cc : 1u);
    size_t obase = (size_t)b * CH * R3 + chunk_lo + vv;
#pragma unroll
    for (int c = 0; c < CH; ++c)
        out1[obase + (size_t)c * R3] = acc[vv * 65 + c] * rcp;
}

// ---------------------------------------------------------------------------
// Fallback (tiny ws): direct atomic accumulate into d_out.
// ---------------------------------------------------------------------------
__global__ __launch_bounds__(256) void accum_direct(
    const float* __restrict__ feat, const float* __restrict__ coords,
    float* __restrict__ out1, uint32* __restrict__ cnt, float* __restrict__ out2)
{
    int gid = blockIdx.x * blockDim.x + threadIdx.x;
    if (gid >= NPOINTS) return;
    int b = gid / NPTS;
    int n = gid - b * NPTS;
    const float* cb = coords + (size_t)b * 3 * NPTS + n;
    float fx = fminf(fmaxf(cb[0]        * 32.0f, 0.0f), 31.0f);
    float fy = fminf(fmaxf(cb[NPTS]     * 32.0f, 0.0f), 31.0f);
    float fz = fminf(fmaxf(cb[2 * NPTS] * 32.0f, 0.0f), 31.0f);
    int x = (int)rintf(fx), y = (int)rintf(fy), z = (int)rintf(fz);
    int v = x * (RR * RR) + y * RR + z;
    float* o2 = out2 + (size_t)b * 3 * NPTS + n;
    o2[0] = (float)x; o2[NPTS] = (float)y; o2[2 * NPTS] = (float)z;
    atomicAdd(&cnt[b * R3 + v], 1u);
    float* obase = out1 + (size_t)(b * CH) * R3 + v;
    const float* frow = feat + (size_t)(b * CH) * NPTS + n;
#pragma unroll 8
    for (int c = 0; c < CH; ++c)
        unsafeAtomicAdd(&obase[(size_t)c * R3], frow[(size_t)c * NPTS]);
}

__global__ __launch_bounds__(256) void finalize_direct(
    float* __restrict__ out1, const uint32* __restrict__ cnt)
{
    size_t gid = (size_t)blockIdx.x * blockDim.x + threadIdx.x;
    size_t total = (size_t)BATCH * CH * R3;
    if (gid >= total) return;
    int v = (int)(gid & (R3 - 1));
    int b = (int)(gid / ((size_t)CH * R3));
    uint32 ct = cnt[b * R3 + v];
    out1[gid] = out1[gid] / (float)(ct > 1u ? ct : 1u);
}

// ---------------------------------------------------------------------------
extern "C" void kernel_launch(void* const* d_in, const int* in_sizes, int n_in,
                              void* d_out, int out_size, void* d_ws, size_t ws_size,
                              hipStream_t stream)
{
    const float* feat   = (const float*)d_in[0];   // [8, 64, 100000]
    const float* coords = (const float*)d_in[1];   // [8, 3, 100000]

    float* out1 = (float*)d_out;                          // [8, 64, 32768]
    float* out2 = out1 + (size_t)BATCH * CH * R3;         // [8, 3, 100000]

    // ws layout
    const size_t vox_off    = 0;
    const size_t vox_bytes  = (size_t)NPOINTS * 2;                 // 1.6 MB
    const size_t featT_off  = (vox_off + vox_bytes + 255) & ~255ull;
    const size_t featT_bytes= (size_t)NPOINTS * CH * 2;            // 102.4 MB
    const size_t need       = featT_off + featT_bytes;

    const int npt_blocks = (NPOINTS + 255) / 256;   // 3125

    if (ws_size >= need) {
        char* ws = (char*)d_ws;
        uint16* vox   = (uint16*)(ws + vox_off);
        uint16* featT = (uint16*)(ws + featT_off);

        voxelize<<<npt_blocks, 256, 0, stream>>>(coords, vox, out2);
        transpose_bf16<<<BATCH * NTILE, 256, 0, stream>>>(feat, featT);
        chunk_reduce<<<BATCH * NCHUNK, 512, CHUNK * 65 * sizeof(float), stream>>>(
            vox, featT, out1);
    } else {
        // fallback: direct atomic accumulate into d_out
        uint32* cnt = (uint32*)d_ws;
        hipMemsetAsync(out1, 0, (size_t)BATCH * CH * R3 * sizeof(float), stream);
        hipMemsetAsync(d_ws, 0, (size_t)NVOX * 4, stream);
        accum_direct<<<npt_blocks, 256, 0, stream>>>(feat, coords, out1, cnt, out2);
        size_t total = (size_t)BATCH * CH * R3;
        finalize_direct<<<(unsigned)((total + 255) / 256), 256, 0, stream>>>(out1, cnt);
    }
}

// Round 3
// 444.960 us; speedup vs baseline: 1.9723x; 1.9723x over previous
//
#include <hip/hip_runtime.h>

#define RR 32
#define R3 32768
#define BATCH 8
#define CH 64
#define NPTS 100000
#define NPOINTS (BATCH * NPTS)   // 800000
#define NVOX (BATCH * R3)        // 262144
#define SCAN_BLOCKS (NVOX / 256) // 1024
#define HBLK 32                  // histogram blocks per batch
#define PPB (NPTS / HBLK)        // 3125 points per hist block

typedef unsigned int uint32;

__device__ __forceinline__ uint32 f2bf(float f) {
    uint32 u = __float_as_uint(f);
    return (u + 0x7fffu + ((u >> 16) & 1u)) >> 16;   // RNE to bf16
}
__device__ __forceinline__ float bf2f(uint32 h) {
    return __uint_as_float(h << 16);
}

// ---------------------------------------------------------------------------
// K1: voxelize + LDS-privatized histogram (NO global atomics).
// 32 blocks per batch, each owns 3125 points; 128 KiB LDS hist; partial
// histograms flushed coalesced to phist (aliased onto the sorted buffer).
// ---------------------------------------------------------------------------
__global__ __launch_bounds__(256) void voxhist(
    const float* __restrict__ coords,  // [B, 3, N]
    uint32* __restrict__ vox,          // [NPOINTS] global voxel id
    uint32* __restrict__ phist,        // [B*HBLK][R3] partial histograms
    float* __restrict__ out2)          // [B, 3, N] voxel coords as float
{
    __shared__ uint32 hist[R3];        // 128 KiB

    int b   = blockIdx.x >> 5;         // 0..7
    int blk = blockIdx.x & 31;         // 0..31
    int tid = threadIdx.x;

    for (int i = tid; i < R3; i += 256) hist[i] = 0u;
    __syncthreads();

    int n0 = blk * PPB;
    const float* cb = coords + (size_t)b * 3 * NPTS;
    float*       o2 = out2   + (size_t)b * 3 * NPTS;

    for (int i = tid; i < PPB; i += 256) {
        int n = n0 + i;
        float fx = fminf(fmaxf(cb[n]            * 32.0f, 0.0f), 31.0f);
        float fy = fminf(fmaxf(cb[NPTS + n]     * 32.0f, 0.0f), 31.0f);
        float fz = fminf(fmaxf(cb[2 * NPTS + n] * 32.0f, 0.0f), 31.0f);
        int x = (int)rintf(fx);   // round-half-even matches jnp.round
        int y = (int)rintf(fy);
        int z = (int)rintf(fz);
        int v = x * (RR * RR) + y * RR + z;

        o2[n]            = (float)x;
        o2[NPTS + n]     = (float)y;
        o2[2 * NPTS + n] = (float)z;

        vox[(size_t)b * NPTS + n] = (uint32)(b * R3 + v);
        atomicAdd(&hist[v], 1u);   // ds_add_u32, no global traffic
    }
    __syncthreads();

    uint32* ph = phist + (size_t)(b * HBLK + blk) * R3;
    for (int i = tid; i < R3; i += 256) ph[i] = hist[i];
}

// ---------------------------------------------------------------------------
// K2: sum the 32 partial histograms per voxel -> cnt, and per-256 block sums.
// ---------------------------------------------------------------------------
__global__ __launch_bounds__(256) void scan_hist_sums(
    const uint32* __restrict__ phist,
    uint32* __restrict__ cnt, uint32* __restrict__ bsum)
{
    __shared__ uint32 s[256];
    int t = threadIdx.x;
    int gid = blockIdx.x * 256 + t;
    int b = gid >> 15;                 // gid / R3
    int v = gid & (R3 - 1);

    const uint32* ph = phist + (size_t)b * HBLK * R3 + v;
    uint32 c = 0;
#pragma unroll
    for (int k = 0; k < HBLK; ++k) c += ph[(size_t)k * R3];
    cnt[gid] = c;

    s[t] = c;
    __syncthreads();
    for (int off = 128; off > 0; off >>= 1) {
        if (t < off) s[t] += s[t + off];
        __syncthreads();
    }
    if (t == 0) bsum[blockIdx.x] = s[0];
}

// ---------------------------------------------------------------------------
// K3: scan over the 1024 block sums (single block).
// ---------------------------------------------------------------------------
__global__ __launch_bounds__(256) void scan_bsum(uint32* __restrict__ bsum)
{
    __shared__ uint32 s[256];
    int t = threadIdx.x;
    uint32 v0 = bsum[4 * t], v1 = bsum[4 * t + 1], v2 = bsum[4 * t + 2], v3 = bsum[4 * t + 3];
    uint32 tot = v0 + v1 + v2 + v3;
    s[t] = tot;
    __syncthreads();
    for (int off = 1; off < 256; off <<= 1) {
        uint32 x = (t >= off) ? s[t - off] : 0u;
        __syncthreads();
        s[t] += x;
        __syncthreads();
    }
    uint32 excl = s[t] - tot;
    bsum[4 * t]     = excl;
    bsum[4 * t + 1] = excl + v0;
    bsum[4 * t + 2] = excl + v0 + v1;
    bsum[4 * t + 3] = excl + v0 + v1 + v2;
}

// ---------------------------------------------------------------------------
// K4: final exclusive scan -> starts[], cursor[].
// ---------------------------------------------------------------------------
__global__ __launch_bounds__(256) void scan_final(
    const uint32* __restrict__ cnt, const uint32* __restrict__ bsum,
    uint32* __restrict__ starts, uint32* __restrict__ cursor)
{
    __shared__ uint32 s[256];
    int t = threadIdx.x;
    int gid = blockIdx.x * 256 + t;
    uint32 v = cnt[gid];
    s[t] = v;
    __syncthreads();
    for (int off = 1; off < 256; off <<= 1) {
        uint32 x = (t >= off) ? s[t - off] : 0u;
        __syncthreads();
        s[t] += x;
        __syncthreads();
    }
    uint32 st = bsum[blockIdx.x] + s[t] - v;   // exclusive
    starts[gid] = st;
    cursor[gid] = st;
}

// ---------------------------------------------------------------------------
// K5: scatter features (bf16x2 packed, 128 B/point) into voxel order.
// (unchanged from the measured 148 us version)
// ---------------------------------------------------------------------------
__global__ __launch_bounds__(256) void phase3_scatter(
    const float* __restrict__ feat,    // [B, C, N]
    const uint32* __restrict__ vox,
    uint32* __restrict__ cursor,
    uint4* __restrict__ sorted)        // [NPOINTS][8] uint4 (= 64 bf16 ch)
{
    int gid = blockIdx.x * blockDim.x + threadIdx.x;
    if (gid >= NPOINTS) return;
    int b = gid / NPTS;
    int n = gid - b * NPTS;

    uint32 g = vox[gid];
    uint32 pos = atomicAdd(&cursor[g], 1u);

    const float* frow = feat + (size_t)b * CH * NPTS + n;
    uint4* dst = sorted + (size_t)pos * 8;
#pragma unroll
    for (int j = 0; j < 8; ++j) {
        uint4 w;
        float f0 = frow[(size_t)(8 * j + 0) * NPTS];
        float f1 = frow[(size_t)(8 * j + 1) * NPTS];
        float f2 = frow[(size_t)(8 * j + 2) * NPTS];
        float f3 = frow[(size_t)(8 * j + 3) * NPTS];
        float f4 = frow[(size_t)(8 * j + 4) * NPTS];
        float f5 = frow[(size_t)(8 * j + 5) * NPTS];
        float f6 = frow[(size_t)(8 * j + 6) * NPTS];
        float f7 = frow[(size_t)(8 * j + 7) * NPTS];
        w.x = f2bf(f0) | (f2bf(f1) << 16);
        w.y = f2bf(f2) | (f2bf(f3) << 16);
        w.z = f2bf(f4) | (f2bf(f5) << 16);
        w.w = f2bf(f6) | (f2bf(f7) << 16);
        dst[j] = w;
    }
}

// ---------------------------------------------------------------------------
// K6: per-block reduce of 64 consecutive voxels, FULL-wave: lane halves take
// even/odd points of the segment (256 B/wave-instr contiguous), combined via
// shfl_xor(32). LDS transpose, coalesced [B,C,R3] write with fused divide.
// ---------------------------------------------------------------------------
__global__ __launch_bounds__(256) void phase4_reduce(
    const uint32* __restrict__ sorted,   // [NPOINTS][32] uint (bf16x2)
    const uint32* __restrict__ starts,
    float* __restrict__ out1)            // [B, C, R3]
{
    __shared__ float tile[64][65];

    int gbase = blockIdx.x * 64;       // global voxel base
    int tid = threadIdx.x;
    int w = tid >> 6, lane = tid & 63;
    int half = lane >> 5;              // 0: even points, 1: odd points
    int cp   = lane & 31;              // channel-pair index

    for (int k = 0; k < 16; ++k) {
        int g = gbase + w * 16 + k;
        uint32 s = starts[g];
        uint32 e = (g == NVOX - 1) ? (uint32)NPOINTS : starts[g + 1];
        float a0 = 0.0f, a1 = 0.0f;
        for (uint32 p = s + half; p < e; p += 2) {
            uint32 d = sorted[(size_t)p * 32 + cp];
            a0 += bf2f(d & 0xffffu);
            a1 += bf2f(d >> 16);
        }
        a0 += __shfl_xor(a0, 32);
        a1 += __shfl_xor(a1, 32);
        if (half == 0) {
            uint32 c = e - s;
            float rcp = 1.0f / (float)(c > 1u ? c : 1u);
            int vloc = w * 16 + k;
            tile[vloc][2 * cp]     = a0 * rcp;
            tile[vloc][2 * cp + 1] = a1 * rcp;
        }
    }
    __syncthreads();

    int b = gbase / R3;
    int v0 = gbase - b * R3;
    int vv = tid & 63;
    int c0 = tid >> 6;
    float* obase = out1 + (size_t)b * CH * R3 + v0 + vv;
#pragma unroll
    for (int jj = 0; jj < 16; ++jj) {
        int c = jj * 4 + c0;
        obase[(size_t)c * R3] = tile[vv][c];
    }
}

// ---------------------------------------------------------------------------
// Fallback paths (small ws): direct atomic kernels.
// ---------------------------------------------------------------------------
__global__ __launch_bounds__(256) void accum_direct(
    const float* __restrict__ feat, const float* __restrict__ coords,
    float* __restrict__ out1, uint32* __restrict__ cnt, float* __restrict__ out2)
{
    int gid = blockIdx.x * blockDim.x + threadIdx.x;
    if (gid >= NPOINTS) return;
    int b = gid / NPTS;
    int n = gid - b * NPTS;
    const float* cb = coords + (size_t)b * 3 * NPTS + n;
    float fx = fminf(fmaxf(cb[0]        * 32.0f, 0.0f), 31.0f);
    float fy = fminf(fmaxf(cb[NPTS]     * 32.0f, 0.0f), 31.0f);
    float fz = fminf(fmaxf(cb[2 * NPTS] * 32.0f, 0.0f), 31.0f);
    int x = (int)rintf(fx), y = (int)rintf(fy), z = (int)rintf(fz);
    int v = x * (RR * RR) + y * RR + z;
    float* o2 = out2 + (size_t)b * 3 * NPTS + n;
    o2[0] = (float)x; o2[NPTS] = (float)y; o2[2 * NPTS] = (float)z;
    atomicAdd(&cnt[b * R3 + v], 1u);
    float* obase = out1 + (size_t)(b * CH) * R3 + v;
    const float* frow = feat + (size_t)(b * CH) * NPTS + n;
#pragma unroll 8
    for (int c = 0; c < CH; ++c)
        unsafeAtomicAdd(&obase[(size_t)c * R3], frow[(size_t)c * NPTS]);
}

__global__ __launch_bounds__(256) void finalize_direct(
    float* __restrict__ out1, const uint32* __restrict__ cnt)
{
    size_t gid = (size_t)blockIdx.x * blockDim.x + threadIdx.x;
    size_t total = (size_t)BATCH * CH * R3;
    if (gid >= total) return;
    int v = (int)(gid & (R3 - 1));
    int b = (int)(gid / ((size_t)CH * R3));
    uint32 ct = cnt[b * R3 + v];
    out1[gid] = out1[gid] / (float)(ct > 1u ? ct : 1u);
}

// ---------------------------------------------------------------------------
extern "C" void kernel_launch(void* const* d_in, const int* in_sizes, int n_in,
                              void* d_out, int out_size, void* d_ws, size_t ws_size,
                              hipStream_t stream)
{
    const float* feat   = (const float*)d_in[0];   // [8, 64, 100000]
    const float* coords = (const float*)d_in[1];   // [8, 3, 100000]

    float* out1 = (float*)d_out;                          // [8, 64, 32768]
    float* out2 = out1 + (size_t)BATCH * CH * R3;         // [8, 3, 100000]

    // ws layout (phist ALIASES the sorted buffer: only live before phase3)
    const size_t vox_off    = 0;
    const size_t vox_bytes  = (size_t)NPOINTS * 4;                 // 3.2 MB
    const size_t cnt_off    = vox_off + ((vox_bytes + 255) & ~255ull);
    const size_t cnt_bytes  = (size_t)NVOX * 4;                    // 1 MB
    const size_t starts_off = cnt_off + ((cnt_bytes + 255) & ~255ull);
    const size_t cursor_off = starts_off + ((cnt_bytes + 255) & ~255ull);
    const size_t bsum_off   = cursor_off + ((cnt_bytes + 255) & ~255ull);
    const size_t bsum_bytes = (size_t)SCAN_BLOCKS * 4;
    const size_t sort_off   = (bsum_off + bsum_bytes + 255) & ~255ull;
    const size_t sort_bytes = (size_t)NPOINTS * 128;               // 102.4 MB
    const size_t need       = sort_off + sort_bytes;
    // phist needs B*HBLK*R3*4 = 32 MB <= sort_bytes: fits inside sorted.

    const int npt_blocks = (NPOINTS + 255) / 256;   // 3125

    if (ws_size >= need) {
        char* ws = (char*)d_ws;
        uint32* vox    = (uint32*)(ws + vox_off);
        uint32* cnt    = (uint32*)(ws + cnt_off);
        uint32* starts = (uint32*)(ws + starts_off);
        uint32* cursor = (uint32*)(ws + cursor_off);
        uint32* bsum   = (uint32*)(ws + bsum_off);
        uint32* sorted = (uint32*)(ws + sort_off);
        uint32* phist  = sorted;                    // alias (dead after K2)

        voxhist<<<BATCH * HBLK, 256, 0, stream>>>(coords, vox, phist, out2);
        scan_hist_sums<<<SCAN_BLOCKS, 256, 0, stream>>>(phist, cnt, bsum);
        scan_bsum<<<1, 256, 0, stream>>>(bsum);
        scan_final<<<SCAN_BLOCKS, 256, 0, stream>>>(cnt, bsum, starts, cursor);
        phase3_scatter<<<npt_blocks, 256, 0, stream>>>(feat, vox, cursor, (uint4*)sorted);
        phase4_reduce<<<NVOX / 64, 256, 0, stream>>>(sorted, starts, out1);
    } else {
        // fallback: direct atomic accumulate into d_out
        uint32* cnt = (uint32*)d_ws;
        hipMemsetAsync(out1, 0, (size_t)BATCH * CH * R3 * sizeof(float), stream);
        hipMemsetAsync(d_ws, 0, (size_t)NVOX * 4, stream);
        accum_direct<<<npt_blocks, 256, 0, stream>>>(feat, coords, out1, cnt, out2);
        size_t total = (size_t)BATCH * CH * R3;
        finalize_direct<<<(unsigned)((total + 255) / 256), 256, 0, stream>>>(out1, cnt);
    }
}